// Round 12
// baseline (234.809 us; speedup 1.0000x reference)
//
#include <hip/hip_runtime.h>
#include <math.h>

typedef __bf16 bf16;
typedef __bf16 bf16x8 __attribute__((ext_vector_type(8)));
typedef __bf16 bf16x4 __attribute__((ext_vector_type(4)));
typedef float floatx4 __attribute__((ext_vector_type(4)));

#define T_SEQ 2048
#define NH 16
#define HD 64
#define HDIM 1024
#define BATCH 2
#define SCALE 0.03125f  // 1/sqrt(1024) per reference

static __device__ __forceinline__ floatx4 mfma16(bf16x8 a, bf16x8 b, floatx4 c) {
  return __builtin_amdgcn_mfma_f32_16x16x32_bf16(a, b, c, 0, 0, 0);
}

static __device__ __forceinline__ bf16x8 cvt_pack(floatx4 lo, floatx4 hi) {
  bf16x8 r;
  r[0] = (bf16)lo[0]; r[1] = (bf16)lo[1]; r[2] = (bf16)lo[2]; r[3] = (bf16)lo[3];
  r[4] = (bf16)hi[0]; r[5] = (bf16)hi[1]; r[6] = (bf16)hi[2]; r[7] = (bf16)hi[3];
  return r;
}

typedef const __attribute__((address_space(1))) void* gas_ptr;
typedef __attribute__((address_space(3))) void* las_ptr;
static __device__ __forceinline__ void load_lds16(const bf16* g, bf16* l) {
  __builtin_amdgcn_global_load_lds((gas_ptr)g, (las_ptr)l, 16, 0, 0);
}

// ---------------------------------------------------------------------------
// cvt: x (4M) and Wq/Wk/Wv (1M each) fp32 -> bf16.  grid (4096, 4) x 256.
// ---------------------------------------------------------------------------
__global__ __launch_bounds__(256) void cvt_f32_bf16(
    const float* __restrict__ x, const float* __restrict__ Wq,
    const float* __restrict__ Wk, const float* __restrict__ Wv,
    bf16* __restrict__ xb, bf16* __restrict__ wb) {
  const int seg = blockIdx.y;
  const float* src; bf16* dst; int n;
  if (seg == 0)      { src = x;  dst = xb;                 n = BATCH * T_SEQ * HDIM; }
  else if (seg == 1) { src = Wq; dst = wb;                 n = HDIM * HDIM; }
  else if (seg == 2) { src = Wk; dst = wb + HDIM * HDIM;   n = HDIM * HDIM; }
  else               { src = Wv; dst = wb + 2*HDIM*HDIM;   n = HDIM * HDIM; }
  const int i4 = (blockIdx.x * 256 + threadIdx.x) * 4;
  if (i4 < n) {
    floatx4 v = *(const floatx4*)(src + i4);
    bf16x4 o; o[0]=(bf16)v[0]; o[1]=(bf16)v[1]; o[2]=(bf16)v[2]; o[3]=(bf16)v[3];
    *(bf16x4*)(dst + i4) = o;
  }
}

// ---------------------------------------------------------------------------
// QKV GEMM, bf16 inputs, proven BK=32 structure (R9).  grid (32, 24).
// Q,K written [b,h,t,d]; V written TRANSPOSED [b,h,d,t] so attention can read
// V B-fragments as single b128 loads (key-contiguous).
// ---------------------------------------------------------------------------
__global__ __launch_bounds__(256) void qkv_gemm_lds(
    const bf16* __restrict__ xb, const bf16* __restrict__ wb,
    const float* __restrict__ bq, const float* __restrict__ bk,
    const float* __restrict__ bv, bf16* __restrict__ qkv) {
  __shared__ __align__(16) bf16 As[128 * 32];
  __shared__ __align__(16) bf16 Bs[128 * 32];

  const int m0  = blockIdx.x * 128;
  const int n0g = blockIdx.y * 128;
  const int z   = n0g >> 10;
  const float* bias = (z == 0) ? bq : (z == 1) ? bk : bv;
  bf16* out = qkv + (size_t)z * BATCH * T_SEQ * HDIM;

  const int lane = threadIdx.x & 63;
  const int w    = threadIdx.x >> 6;
  const int l15  = lane & 15;
  const int quad = lane >> 4;
  const int wm = w & 1, wn = w >> 1;

  const int srow = w * 32 + (lane >> 2);
  const int scol = (lane & 3) * 8;
  const bf16* aG0 = xb + (size_t)(m0 + srow) * HDIM + scol;
  const bf16* aG1 = xb + (size_t)(m0 + srow + 16) * HDIM + scol;
  const bf16* bG0 = wb + (size_t)(n0g + srow) * HDIM + scol;
  const bf16* bG1 = wb + (size_t)(n0g + srow + 16) * HDIM + scol;
  bf16* aL0 = As + (w * 32) * 32;
  bf16* aL1 = As + (w * 32 + 16) * 32;
  bf16* bL0 = Bs + (w * 32) * 32;
  bf16* bL1 = Bs + (w * 32 + 16) * 32;

  floatx4 acc[4][4] = {};

  for (int k0 = 0; k0 < HDIM; k0 += 32) {
    __syncthreads();
    load_lds16(aG0 + k0, aL0);
    load_lds16(aG1 + k0, aL1);
    load_lds16(bG0 + k0, bL0);
    load_lds16(bG1 + k0, bL1);
    __syncthreads();

    bf16x8 af[4], bff[4];
    for (int i = 0; i < 4; ++i)
      af[i] = *(const bf16x8*)(As + (wm * 64 + i * 16 + l15) * 32 + quad * 8);
    for (int jj = 0; jj < 4; ++jj)
      bff[jj] = *(const bf16x8*)(Bs + (wn * 64 + jj * 16 + l15) * 32 + quad * 8);
    for (int i = 0; i < 4; ++i)
      for (int jj = 0; jj < 4; ++jj)
        acc[i][jj] = mfma16(af[i], bff[jj], acc[i][jj]);
  }

  for (int jj = 0; jj < 4; ++jj) {
    const int nloc = (n0g + wn * 64 + jj * 16 + l15) & (HDIM - 1);
    const float bvv = bias[nloc];
    const int h = nloc >> 6, d = nloc & (HD - 1);
    if (z != 2) {
      for (int i = 0; i < 4; ++i) {
        for (int r = 0; r < 4; ++r) {
          const int gm = m0 + wm * 64 + i * 16 + quad * 4 + r;
          const int bb = gm >> 11, t = gm & (T_SEQ - 1);
          out[((size_t)((bb * NH + h) * T_SEQ) + t) * HD + d] = (bf16)(acc[i][jj][r] + bvv);
        }
      }
    } else {  // V: [b,h,d,t] (t-contiguous -> bf16x4 stores)
      for (int i = 0; i < 4; ++i) {
        const int gm0 = m0 + wm * 64 + i * 16 + quad * 4;
        const int bb = gm0 >> 11, t0 = gm0 & (T_SEQ - 1);
        bf16x4 vv;
        for (int r = 0; r < 4; ++r) vv[r] = (bf16)(acc[i][jj][r] + bvv);
        *(bf16x4*)(out + ((size_t)(bb * NH + h) * HD + d) * T_SEQ + t0) = vv;
      }
    }
  }
}

// ---------------------------------------------------------------------------
// Fallback QKV GEMM (fp32 staging) for small workspaces; V transposed too.
// ---------------------------------------------------------------------------
#define LSTR 40

__global__ __launch_bounds__(256) void qkv_gemm_f32(
    const float* __restrict__ x,
    const float* __restrict__ Wq, const float* __restrict__ bq,
    const float* __restrict__ Wk, const float* __restrict__ bk,
    const float* __restrict__ Wv, const float* __restrict__ bv,
    bf16* __restrict__ qkv) {
  __shared__ __align__(16) bf16 As[128 * LSTR];
  __shared__ __align__(16) bf16 Bs[128 * LSTR];

  const int n0g = blockIdx.y * 128;
  const int z   = n0g >> 10;
  const int n0  = n0g & (HDIM - 1);
  const float* W    = (z == 0) ? Wq : (z == 1) ? Wk : Wv;
  const float* bias = (z == 0) ? bq : (z == 1) ? bk : bv;
  bf16* out = qkv + (size_t)z * BATCH * T_SEQ * HDIM;
  const int m0 = blockIdx.x * 128;

  const int lane = threadIdx.x & 63;
  const int w    = threadIdx.x >> 6;
  const int l15  = lane & 15;
  const int quad = lane >> 4;
  const int wm = w & 1, wn = w >> 1;

  const int srow  = threadIdx.x >> 1;
  const int shalf = threadIdx.x & 1;
  const float* aSrc = x + (size_t)(m0 + srow) * HDIM + shalf * 16;
  const float* bSrc = W + (size_t)(n0 + srow) * HDIM + shalf * 16;
  bf16* aDst = As + srow * LSTR + shalf * 16;
  bf16* bDst = Bs + srow * LSTR + shalf * 16;

  floatx4 acc[4][4] = {};

  for (int k0 = 0; k0 < HDIM; k0 += 32) {
    floatx4 a0 = *(const floatx4*)(aSrc + k0);
    floatx4 a1 = *(const floatx4*)(aSrc + k0 + 4);
    floatx4 a2 = *(const floatx4*)(aSrc + k0 + 8);
    floatx4 a3 = *(const floatx4*)(aSrc + k0 + 12);
    floatx4 b0 = *(const floatx4*)(bSrc + k0);
    floatx4 b1 = *(const floatx4*)(bSrc + k0 + 4);
    floatx4 b2 = *(const floatx4*)(bSrc + k0 + 8);
    floatx4 b3 = *(const floatx4*)(bSrc + k0 + 12);

    __syncthreads();
    *(bf16x8*)(aDst)     = cvt_pack(a0, a1);
    *(bf16x8*)(aDst + 8) = cvt_pack(a2, a3);
    *(bf16x8*)(bDst)     = cvt_pack(b0, b1);
    *(bf16x8*)(bDst + 8) = cvt_pack(b2, b3);
    __syncthreads();

    bf16x8 af[4], bff[4];
    for (int i = 0; i < 4; ++i)
      af[i] = *(const bf16x8*)(As + (wm * 64 + i * 16 + l15) * LSTR + quad * 8);
    for (int jj = 0; jj < 4; ++jj)
      bff[jj] = *(const bf16x8*)(Bs + (wn * 64 + jj * 16 + l15) * LSTR + quad * 8);
    for (int i = 0; i < 4; ++i)
      for (int jj = 0; jj < 4; ++jj)
        acc[i][jj] = mfma16(af[i], bff[jj], acc[i][jj]);
  }

  for (int jj = 0; jj < 4; ++jj) {
    const int nloc = n0 + wn * 64 + jj * 16 + l15;
    const float bvv = bias[nloc];
    const int h = nloc >> 6, d = nloc & (HD - 1);
    if (z != 2) {
      for (int i = 0; i < 4; ++i) {
        for (int r = 0; r < 4; ++r) {
          const int gm = m0 + wm * 64 + i * 16 + quad * 4 + r;
          const int bb = gm >> 11, t = gm & (T_SEQ - 1);
          out[((size_t)((bb * NH + h) * T_SEQ) + t) * HD + d] = (bf16)(acc[i][jj][r] + bvv);
        }
      }
    } else {
      for (int i = 0; i < 4; ++i) {
        const int gm0 = m0 + wm * 64 + i * 16 + quad * 4;
        const int bb = gm0 >> 11, t0 = gm0 & (T_SEQ - 1);
        bf16x4 vv;
        for (int r = 0; r < 4; ++r) vv[r] = (bf16)(acc[i][jj][r] + bvv);
        *(bf16x4*)(out + ((size_t)(bb * NH + h) * HD + d) * T_SEQ + t0) = vv;
      }
    }
  }
}

// ---------------------------------------------------------------------------
// Attention v5: barrier-free, fixed-m softmax, V-transposed b128 loads,
// wave-perfect balance.  Block = 128 thr (2 waves); wave owns the q-tile
// PAIR {p, 127-p} (p = blockIdx.y*2 + w) -> exactly 65-66 kv-steps per wave.
// grid (B*NH=32, 32) = 1024 blocks, 4/CU.
// V in [b,h,d,t]: B-frag = 8 consecutive keys at fixed d -> one b128/dt.
// ---------------------------------------------------------------------------
#define PSTR 40

__global__ __launch_bounds__(128) void attn_v5(
    const bf16* __restrict__ qkv, float* __restrict__ out) {
  const bf16* Q  = qkv;
  const bf16* K  = qkv + (size_t)BATCH * T_SEQ * HDIM;
  const bf16* Vt = K + (size_t)BATCH * T_SEQ * HDIM;   // [b,h,d,t]

  __shared__ __align__(16) bf16 pl[2 * 16 * PSTR];

  const int lane = threadIdx.x & 63;
  const int w    = threadIdx.x >> 6;       // 0..1
  const int l15  = lane & 15;
  const int quad = lane >> 4;

  const int bh = blockIdx.x;
  const int p  = blockIdx.y * 2 + w;       // 0..63
  const bf16* Qb  = Q  + (size_t)bh * T_SEQ * HD;
  const bf16* Kb  = K  + (size_t)bh * T_SEQ * HD;
  const bf16* Vtb = Vt + (size_t)bh * HD * T_SEQ;
  const int b = bh >> 4, h = bh & (NH - 1);

  bf16* pw = pl + w * 16 * PSTR;

  for (int half = 0; half < 2; ++half) {
    const int qt = (half == 0) ? p : (127 - p);
    const int q0 = qt * 16;

    bf16x8 qf0 = *(const bf16x8*)(Qb + (size_t)(q0 + l15) * HD + quad * 8);
    bf16x8 qf1 = *(const bf16x8*)(Qb + (size_t)(q0 + l15) * HD + 32 + quad * 8);
    for (int e = 0; e < 8; ++e) {  // pre-scale by 1/32 (exact in bf16)
      qf0[e] = (bf16)((float)qf0[e] * SCALE);
      qf1[e] = (bf16)((float)qf1[e] * SCALE);
    }

    floatx4 o[4] = {};
    float lacc[4] = {0.f, 0.f, 0.f, 0.f};
    const int S = (qt >> 1) + 1;

    for (int s0 = 0; s0 < S; ++s0) {
      const int kv = s0 * 32;

      // V B-frags: one b128 per dt (8 consecutive keys at row d)
      bf16x8 ve[4];
      for (int dt = 0; dt < 4; ++dt)
        ve[dt] = *(const bf16x8*)(Vtb + (size_t)(dt * 16 + l15) * T_SEQ + kv + quad * 8);

      // S = Q K^T (pre-scaled), two 16-key n-tiles
      floatx4 sa[2];
      for (int nt = 0; nt < 2; ++nt) {
        const int kbase = kv + nt * 16;
        bf16x8 k0 = *(const bf16x8*)(Kb + (size_t)(kbase + l15) * HD + quad * 8);
        bf16x8 k1 = *(const bf16x8*)(Kb + (size_t)(kbase + l15) * HD + 32 + quad * 8);
        floatx4 s = {};
        s = mfma16(qf0, k0, s);
        s = mfma16(qf1, k1, s);
        sa[nt] = s;
      }

      // p = exp(s), fixed m=0; mask only the diagonal step (wave-uniform)
      float pp[2][4];
      for (int nt = 0; nt < 2; ++nt)
        for (int r = 0; r < 4; ++r) pp[nt][r] = __expf(sa[nt][r]);
      if (s0 == S - 1) {
        for (int nt = 0; nt < 2; ++nt) {
          const int kg = kv + nt * 16 + l15;
          for (int r = 0; r < 4; ++r) {
            const int qg = q0 + quad * 4 + r;
            if (kg > qg) pp[nt][r] = 0.f;
          }
        }
      }
      for (int r = 0; r < 4; ++r) lacc[r] += pp[0][r] + pp[1][r];

      // P: C-layout -> A-layout via per-wave LDS slice (same-wave, in-order)
      for (int nt = 0; nt < 2; ++nt)
        for (int r = 0; r < 4; ++r)
          pw[(quad * 4 + r) * PSTR + nt * 16 + l15] = (bf16)pp[nt][r];
      __asm__ __volatile__("s_waitcnt lgkmcnt(0)" ::: "memory");
      const bf16x8 pf = *(const bf16x8*)(pw + l15 * PSTR + quad * 8);

      // O += P V
      for (int dt = 0; dt < 4; ++dt) o[dt] = mfma16(pf, ve[dt], o[dt]);
    }

    // l: one shuffle reduction over the 16 key-lanes (per quad)
    for (int r = 0; r < 4; ++r) {
      float v = lacc[r];
      for (int off = 1; off < 16; off <<= 1) v += __shfl_xor(v, off, 64);
      lacc[r] = v;
    }

    for (int dt = 0; dt < 4; ++dt) {
      for (int r = 0; r < 4; ++r) {
        const int t = q0 + quad * 4 + r;
        out[((size_t)(b * T_SEQ + t) * HDIM) + h * HD + dt * 16 + l15] =
            o[dt][r] / lacc[r];
      }
    }
  }
}

// ---------------------------------------------------------------------------
extern "C" void kernel_launch(void* const* d_in, const int* in_sizes, int n_in,
                              void* d_out, int out_size, void* d_ws, size_t ws_size,
                              hipStream_t stream) {
  const float* x  = (const float*)d_in[0];
  const float* Wq = (const float*)d_in[1];
  const float* bq = (const float*)d_in[2];
  const float* Wk = (const float*)d_in[3];
  const float* bk = (const float*)d_in[4];
  const float* Wv = (const float*)d_in[5];
  const float* bv = (const float*)d_in[6];
  float* out = (float*)d_out;

  const size_t elems = (size_t)BATCH * T_SEQ * HDIM;   // 4M
  bf16* qkv  = (bf16*)d_ws;                            // 24 MB
  bf16* xbuf = qkv + 3 * elems;                        // +8 MB
  bf16* wbuf = xbuf + elems;                           // +6 MB

  const bool fast = ws_size >= (size_t)39 * 1024 * 1024;
  dim3 g1(BATCH * T_SEQ / 128, 3 * HDIM / 128);
  if (fast) {
    cvt_f32_bf16<<<dim3(4096, 4), 256, 0, stream>>>(x, Wq, Wk, Wv, xbuf, wbuf);
    qkv_gemm_lds<<<g1, 256, 0, stream>>>(xbuf, wbuf, bq, bk, bv, qkv);
  } else {
    qkv_gemm_f32<<<g1, 256, 0, stream>>>(x, Wq, bq, Wk, bk, Wv, bv, qkv);
  }

  attn_v5<<<dim3(BATCH * NH, 32), 128, 0, stream>>>(qkv, out);
}